// Round 19
// baseline (96.549 us; speedup 1.0000x reference)
//
#include <hip/hip_runtime.h>
#include <hip/hip_bf16.h>

#define BB 8
#define NN 8192
#define MM 2048
#define C1 64
#define C2 128
#define CIN 192
#define CO 128
#define NB (BB*NN)
#define EPS 1e-5f

typedef unsigned short u16;
typedef unsigned int u32;
typedef unsigned long long u64;
typedef __bf16 bf16_t;
typedef bf16_t bf16x8 __attribute__((ext_vector_type(8)));
typedef float f32x4 __attribute__((ext_vector_type(4)));

static __device__ __forceinline__ float b2f(u16 u) { return __uint_as_float(((u32)u) << 16); }
static __device__ __forceinline__ u16 f2b(float f) {
    __hip_bfloat16 h = __float2bfloat16(f);
    u16 u; __builtin_memcpy(&u, &h, 2); return u;
}

// ---------------- weights f32 -> bf16 (same layout) ----------------
__global__ void k_prep_w(const float* __restrict__ W0, const float* __restrict__ W1,
                         u16* __restrict__ W0b, u16* __restrict__ W1b) {
    int t = blockIdx.x * 256 + threadIdx.x;
    if (t < CIN * CO) W0b[t] = f2b(W0[t]);
    if (t < CO * CO)  W1b[t] = f2b(W1[t]);
}

// ---------------- high_feats transpose: f32 [B][C2][M] -> bf16 [B][M][C2] ----------------
__global__ void k_prep_h(const float* __restrict__ hf, u16* __restrict__ hT) {
    __shared__ u16 s[64][65];
    int b = blockIdx.x, m0 = blockIdx.y * 64, c0 = blockIdx.z * 64;
    for (int e = threadIdx.x; e < 64 * 64; e += 256) {
        int i = e >> 6, j = e & 63;                 // i: c, j: m (coalesced in m)
        s[i][j] = f2b(hf[(b * C2 + c0 + i) * MM + m0 + j]);
    }
    __syncthreads();
    for (int e = threadIdx.x; e < 64 * 64; e += 256) {
        int ii = e & 63, jj = e >> 6;               // coalesced in c
        hT[(b * MM + m0 + jj) * C2 + c0 + ii] = s[ii][jj];
    }
}

// ---------------- nearest neighbor: 2-phase exact argmin, Q=4 queries/thread ----------------
// R18-proven structure rebalanced: 1024 blocks (4/CU, 4 waves/SIMD) x 16 parts x
// 16 groups x Q=4. Per-CU DS halves vs R18 (~5us); VALU 48 ops/iter across 8
// independent min-chains (ILP). Phase 1: pure fminf over d2 (sqrt_rn monotone =>
// min sqrt = sqrt(min d2)), no index bookkeeping. Phase 2 exact np first-index:
// s_min = min over parts of sqrt_rn(m2_p); FIRST tying part provably contains the
// np argmin; 16 lanes cooperatively rescan it (bank-rotated, order-independent
// first-index via min(pred ? idx : INF)). d2 via rn mul,mul,add == np (no FMA).
__global__ __launch_bounds__(256) void k_argmin(
        const float* __restrict__ lt_, const float* __restrict__ lp_,
        const float* __restrict__ ht_, const float* __restrict__ hp_,
        int* __restrict__ idx) {
    __shared__ float2 hs[16 * 130];                 // stride 130: 2-way bank alias (free)
    int b = blockIdx.x >> 7;                        // 128 blocks per batch
    int n0 = (blockIdx.x & 127) << 6;               // 64 queries per block
    int tid = threadIdx.x;
    for (int e = tid; e < MM; e += 256) {
        int p = e >> 7, i = e & 127;
        hs[p * 130 + i] = make_float2(ht_[b * MM + e], hp_[b * MM + e]);
    }
    __syncthreads();
    int g = tid >> 4, p = tid & 15;                 // 16 query-groups x 16 m-parts
    int gw = (tid & 63) >> 4;                       // group within wave (for ballot)
    int qbase = n0 + (g << 2);
    float qt[4], qp[4];
#pragma unroll
    for (int j = 0; j < 4; ++j) {
        qt[j] = lt_[b * NN + qbase + j];
        qp[j] = lp_[b * NN + qbase + j];
    }
    // ---- phase 1: pure min over this part's 128 candidates, 4 queries ----
    float me[4], mo[4];
#pragma unroll
    for (int j = 0; j < 4; ++j) { me[j] = 1e30f; mo[j] = 1e30f; }
    const float2* hp2 = &hs[p * 130];
#pragma unroll 4
    for (int k = 0; k < 64; ++k) {                  // 2 cands/iter via ds_read_b128
        f32x4 v = *(const f32x4*)&hp2[k * 2];       // {xA,yA,xB,yB}
#pragma unroll
        for (int j = 0; j < 4; ++j) {
            float dtA = qt[j] - v[0], dpA = qp[j] - v[1];
            me[j] = fminf(me[j], __fadd_rn(__fmul_rn(dtA, dtA), __fmul_rn(dpA, dpA)));
            float dtB = qt[j] - v[2], dpB = qp[j] - v[3];
            mo[j] = fminf(mo[j], __fadd_rn(__fmul_rn(dtB, dtB), __fmul_rn(dpB, dpB)));
        }
    }
    // ---- per-part min sqrt; merge s_min over 16 parts (lane bits 0-3) ----
    float sp[4], s[4];
#pragma unroll
    for (int j = 0; j < 4; ++j) {
        sp[j] = __fsqrt_rn(fminf(me[j], mo[j]));
        s[j] = sp[j];
#pragma unroll
        for (int d = 1; d <= 8; d <<= 1)
            s[j] = fminf(s[j], __shfl_xor(s[j], d, 64));
    }
    // ---- first tying part per query ----
    int P[4];
#pragma unroll
    for (int j = 0; j < 4; ++j) {
        u64 bm = __ballot(sp[j] == s[j]);
        P[j] = __ffs((int)((bm >> (gw * 16)) & 0xffffULL)) - 1;
    }
    // ---- phase 2: cooperative rescan of part P[j] (8 cands per lane) ----
#pragma unroll
    for (int j = 0; j < 4; ++j) {
        int f = 0x7fffffff;
        const float2* r = &hs[P[j] * 130 + (p << 3)];
#pragma unroll
        for (int k = 0; k < 4; ++k) {
            int kk = (k + p) & 3;                   // bank-rotated; order-independent
            f32x4 v = *(const f32x4*)&r[kk * 2];
            int lc = (p << 3) + (kk << 1);
            float dtA = qt[j] - v[0], dpA = qp[j] - v[1];
            float sA = __fsqrt_rn(__fadd_rn(__fmul_rn(dtA, dtA), __fmul_rn(dpA, dpA)));
            f = min(f, (sA == s[j]) ? lc : 0x7fffffff);
            float dtB = qt[j] - v[2], dpB = qp[j] - v[3];
            float sB = __fsqrt_rn(__fadd_rn(__fmul_rn(dtB, dtB), __fmul_rn(dpB, dpB)));
            f = min(f, (sB == s[j]) ? lc + 1 : 0x7fffffff);
        }
#pragma unroll
        for (int d = 1; d <= 8; d <<= 1)            // first tying local idx over lanes
            f = min(f, __shfl_xor(f, d, 64));
        if (p == 0) idx[b * NN + qbase + j] = (P[j] << 7) + f;
    }
}

// epilogue: bias add, per-channel sum/sumsq into LDS chs/chq, bf16 store to ylds
static __device__ __forceinline__ void epilogue(
        f32x4* ac0, f32x4* ac1, const float* bias, u16* yl,
        float* chs, float* chq, int w, int ln, int q) {
#pragma unroll
    for (int mf = 0; mf < 2; ++mf) {
        f32x4* A = mf ? ac1 : ac0;
        int chb = 32 * w + 16 * mf + 4 * q;
        float bs[4], ss[4] = {0.f, 0.f, 0.f, 0.f}, sq[4] = {0.f, 0.f, 0.f, 0.f};
#pragma unroll
        for (int r = 0; r < 4; ++r) bs[r] = bias[chb + r];
#pragma unroll
        for (int nf = 0; nf < 4; ++nf) {
            int n = (nf << 4) + ln;
#pragma unroll
            for (int r = 0; r < 4; ++r) {
                float y = A[nf][r] + bs[r];
                ss[r] += y; sq[r] += y * y;
                int o = chb + r;
                yl[(o << 6) + (n ^ ((o & 7) << 3))] = f2b(y);
            }
        }
#pragma unroll
        for (int r = 0; r < 4; ++r) {
            float v = ss[r], u2 = sq[r];
#pragma unroll
            for (int d = 1; d < 16; d <<= 1) {
                v += __shfl_xor(v, d, 64);
                u2 += __shfl_xor(u2, d, 64);
            }
            if (ln == 0) { atomicAdd(&chs[chb + r], v); atomicAdd(&chq[chb + r], u2); }
        }
    }
}

// ---------------- deterministic stat reduce: gpart[1024][256] -> gout[256] ----------------
__global__ __launch_bounds__(256) void k_red(const float* __restrict__ gpart,
                                             float* __restrict__ gout) {
    __shared__ float part[4];
    int c = blockIdx.x;                    // one block per channel-slot (256)
    int t = threadIdx.x;
    float s = 0.f;
#pragma unroll
    for (int k = 0; k < 4; ++k)
        s += gpart[(t + (k << 8)) * 256 + c];
#pragma unroll
    for (int d = 1; d < 64; d <<= 1)
        s += __shfl_xor(s, d, 64);
    if ((t & 63) == 0) part[t >> 6] = s;
    __syncthreads();
    if (t == 0) gout[c] = (part[0] + part[1]) + (part[2] + part[3]);
}

// ---------------- layer 0: gather + MFMA gemm + bias -> y0 (ws, bf16) + stat partials ----------------
__global__ __launch_bounds__(256) void k_l0(
        const float* __restrict__ lf, const u16* __restrict__ hT, const int* __restrict__ idx,
        const u16* __restrict__ W0b, const float* __restrict__ b0,
        u16* __restrict__ y0, float* __restrict__ gpart) {
    __shared__ u16 xt[64 * CIN];          // B-tile [n][k] XOR-chunk-swizzled (24.5KB)
    __shared__ u16 ylds[CO * 64];         // y tile [o][n swz] (16KB)
    __shared__ float chs[CO], chq[CO];
    __shared__ int idxs[64];
    int tid = threadIdx.x;
    int l = tid & 63, w = tid >> 6, ln = l & 15, q = l >> 4;
    int b = blockIdx.x >> 7, n0 = (blockIdx.x & 127) << 6;
    if (tid < 64) idxs[tid] = idx[b * NN + n0 + tid];
    if (tid < 128) { chs[tid] = 0.f; chq[tid] = 0.f; }
    __syncthreads();
    // stage low_feats rows 0..63 via in-register transpose (lane = channel, f32 -> bf16)
    {
        const float* src = lf + (size_t)(b * C1 + l) * NN + n0 + (w << 4);
        float4 f0 = *(const float4*)src;
        float4 f1 = *(const float4*)(src + 4);
        float4 f2 = *(const float4*)(src + 8);
        float4 f3 = *(const float4*)(src + 12);
        float v[16] = {f0.x, f0.y, f0.z, f0.w, f1.x, f1.y, f1.z, f1.w,
                       f2.x, f2.y, f2.z, f2.w, f3.x, f3.y, f3.z, f3.w};
        int cc = l >> 3, clo = l & 7;
#pragma unroll
        for (int i = 0; i < 16; ++i) {
            int n = (w << 4) + i;
            xt[n * CIN + ((cc ^ (i & 7)) << 3) + clo] = f2b(v[i]);
        }
    }
    // gather nearest high rows (contiguous 256B per row from bf16 hT)
    for (int e = tid; e < 1024; e += 256) {
        int n = e >> 4, c16 = e & 15;
        uint4 v = *(const uint4*)(hT + (size_t)(b * MM + idxs[n]) * C2 + (c16 << 3));
        *(uint4*)&xt[n * CIN + (((8 + c16) ^ (n & 7)) << 3)] = v;
    }
    __syncthreads();
    f32x4 ac0[4], ac1[4];
#pragma unroll
    for (int nf = 0; nf < 4; ++nf) {
        ac0[nf] = f32x4{0.f, 0.f, 0.f, 0.f};
        ac1[nf] = f32x4{0.f, 0.f, 0.f, 0.f};
    }
    const u16* w0r0 = W0b + (32 * w + ln) * CIN + 8 * q;
    const u16* w0r1 = w0r0 + 16 * CIN;
#pragma unroll
    for (int s = 0; s < 6; ++s) {
        bf16x8 a0 = *(const bf16x8*)(w0r0 + 32 * s);
        bf16x8 a1 = *(const bf16x8*)(w0r1 + 32 * s);
#pragma unroll
        for (int nf = 0; nf < 4; ++nf) {
            bf16x8 bv = *(const bf16x8*)&xt[(16 * nf + ln) * CIN + (((4 * s + q) ^ (ln & 7)) << 3)];
            ac0[nf] = __builtin_amdgcn_mfma_f32_16x16x32_bf16(a0, bv, ac0[nf], 0, 0, 0);
            ac1[nf] = __builtin_amdgcn_mfma_f32_16x16x32_bf16(a1, bv, ac1[nf], 0, 0, 0);
        }
    }
    epilogue(ac0, ac1, b0, ylds, chs, chq, w, ln, q);
    __syncthreads();
    // per-block stat partials: unique coalesced slot, no global atomics
    gpart[blockIdx.x * 256 + tid] = (tid < 128) ? chs[tid] : chq[tid - 128];
    // coalesced store ylds -> y0 (ws, bf16)
    {
        int o = tid >> 1, h = tid & 1;
#pragma unroll
        for (int jj = 0; jj < 4; ++jj) {
            int j = (h << 2) + jj;
            uint4 v = *(const uint4*)&ylds[(o << 6) + ((j ^ (o & 7)) << 3)];
            *(uint4*)(y0 + (size_t)(b * CO + o) * NN + n0 + (j << 3)) = v;
        }
    }
}

// ---------------- layer 1: BN0+ReLU on y0 tile -> MFMA gemm -> y1pre in place + stat partials ----------------
__global__ __launch_bounds__(256) void k_l1(
        u16* __restrict__ y, const float* __restrict__ g0, const float* __restrict__ be0,
        const u16* __restrict__ W1b, const float* __restrict__ b1,
        const float* __restrict__ gstat, float* __restrict__ gpart) {
    __shared__ u16 xt[64 * CO];           // B-tile [n][k] swz (16KB)
    __shared__ u16 ylds[CO * 64];         // (16KB)
    __shared__ float chs[CO], chq[CO], sc[CO], sh[CO];
    int tid = threadIdx.x;
    int l = tid & 63, w = tid >> 6, ln = l & 15, q = l >> 4;
    int b = blockIdx.x >> 7, n0 = (blockIdx.x & 127) << 6;
    if (tid < 128) {
        float s = gstat[tid], qv = gstat[128 + tid];   // complete: dispatch boundary
        float mu = s * (1.f / NB);
        float var = qv * (1.f / NB) - mu * mu;
        float istd = 1.f / __fsqrt_rn(var + EPS);
        float scale = g0[tid] * istd;
        sc[tid] = scale;
        sh[tid] = be0[tid] - mu * scale;
        chs[tid] = 0.f; chq[tid] = 0.f;
    }
    __syncthreads();
    // stage y0 tile with BN0+ReLU via in-register transpose; 2 x 64 channels
#pragma unroll
    for (int it = 0; it < 2; ++it) {
        int c = (it << 6) + l;
        const u16* src = y + (size_t)(b * CO + c) * NN + n0 + (w << 4);
        uint4 r0 = *(const uint4*)src;
        uint4 r1 = *(const uint4*)(src + 8);
        u16 raw[16];
        *(uint4*)&raw[0] = r0;
        *(uint4*)&raw[8] = r1;
        float scale = sc[c], shift = sh[c];
        int cc = c >> 3, clo = c & 7;
#pragma unroll
        for (int i = 0; i < 16; ++i) {
            int n = (w << 4) + i;
            float hv = fmaxf(b2f(raw[i]) * scale + shift, 0.f);
            xt[(n << 7) + ((cc ^ (i & 7)) << 3) + clo] = f2b(hv);
        }
    }
    __syncthreads();
    f32x4 ac0[4], ac1[4];
#pragma unroll
    for (int nf = 0; nf < 4; ++nf) {
        ac0[nf] = f32x4{0.f, 0.f, 0.f, 0.f};
        ac1[nf] = f32x4{0.f, 0.f, 0.f, 0.f};
    }
    const u16* w1r0 = W1b + (32 * w + ln) * CO + 8 * q;
    const u16* w1r1 = w1r0 + 16 * CO;
#pragma unroll
    for (int s = 0; s < 4; ++s) {
        bf16x8 a0 = *(const bf16x8*)(w1r0 + 32 * s);
        bf16x8 a1 = *(const bf16x8*)(w1r1 + 32 * s);
#pragma unroll
        for (int nf = 0; nf < 4; ++nf) {
            bf16x8 bv = *(const bf16x8*)&xt[((16 * nf + ln) << 7) + (((4 * s + q) ^ (ln & 7)) << 3)];
            ac0[nf] = __builtin_amdgcn_mfma_f32_16x16x32_bf16(a0, bv, ac0[nf], 0, 0, 0);
            ac1[nf] = __builtin_amdgcn_mfma_f32_16x16x32_bf16(a1, bv, ac1[nf], 0, 0, 0);
        }
    }
    epilogue(ac0, ac1, b1, ylds, chs, chq, w, ln, q);
    __syncthreads();
    gpart[blockIdx.x * 256 + tid] = (tid < 128) ? chs[tid] : chq[tid - 128];
    // in-place store y1pre (bf16) over the same tile of ws
    {
        int o = tid >> 1, h = tid & 1;
#pragma unroll
        for (int jj = 0; jj < 4; ++jj) {
            int j = (h << 2) + jj;
            uint4 v = *(const uint4*)&ylds[(o << 6) + ((j ^ (o & 7)) << 3)];
            *(uint4*)(y + (size_t)(b * CO + o) * NN + n0 + (j << 3)) = v;
        }
    }
}

// ---------------- final BN1 + ReLU: y1pre (bf16, ws) -> d_out (f32) ----------------
__global__ __launch_bounds__(256) void k_bn1(
        const u16* __restrict__ y, const float* __restrict__ gstat,
        const float* __restrict__ g1, const float* __restrict__ be1,
        float* __restrict__ out) {
    int t = blockIdx.x * 256 + threadIdx.x;   // 4096 blocks: 8 elems/thread
    int o = (t >> 10) & 127;
    float s = gstat[256 + o], qv = gstat[384 + o];
    float mu = s * (1.f / NB);
    float var = qv * (1.f / NB) - mu * mu;
    float istd = 1.f / __fsqrt_rn(var + EPS);
    float scale = g1[o] * istd;
    float shift = be1[o] - mu * scale;
    size_t e0 = (size_t)t << 3;
    uint4 v = *(const uint4*)(y + e0);
    u16 raw[8];
    *(uint4*)raw = v;
    float r[8];
#pragma unroll
    for (int k = 0; k < 8; ++k)
        r[k] = fmaxf(b2f(raw[k]) * scale + shift, 0.f);
    *(float4*)(out + e0) = make_float4(r[0], r[1], r[2], r[3]);
    *(float4*)(out + e0 + 4) = make_float4(r[4], r[5], r[6], r[7]);
}

extern "C" void kernel_launch(void* const* d_in, const int* in_sizes, int n_in,
                              void* d_out, int out_size, void* d_ws, size_t ws_size,
                              hipStream_t stream) {
    const float* lt = (const float*)d_in[0];
    const float* lp = (const float*)d_in[1];
    const float* lf = (const float*)d_in[2];
    const float* ht = (const float*)d_in[3];
    const float* hp = (const float*)d_in[4];
    const float* hf = (const float*)d_in[5];
    const float* W0 = (const float*)d_in[6];
    const float* b0 = (const float*)d_in[7];
    const float* g0 = (const float*)d_in[8];
    const float* be0 = (const float*)d_in[9];
    const float* W1 = (const float*)d_in[10];
    const float* b1 = (const float*)d_in[11];
    const float* g1 = (const float*)d_in[12];
    const float* be1 = (const float*)d_in[13];

    char* ws = (char*)d_ws;
    u16* y0 = (u16*)ws;                         // 16.78 MB (y0, then y1pre in place)
    u16* hT = (u16*)(ws + 16777216);            // 4.19 MB
    int* idx = (int*)(ws + 20971520);           // 256 KB
    float* gstat = (float*)(ws + 21233664);     // 2 KB: [0:256]=L0 stats, [256:512]=L1
    u16* W0b = (u16*)(ws + 21235712);           // 48 KB
    u16* W1b = (u16*)(ws + 21284864);           // 32 KB
    float* gpart = (float*)(ws + 21317632);     // 1 MB per-block stat partials (reused)

    k_prep_w<<<96, 256, 0, stream>>>(W0, W1, W0b, W1b);
    k_prep_h<<<dim3(8, 32, 2), 256, 0, stream>>>(hf, hT);
    k_argmin<<<1024, 256, 0, stream>>>(lt, lp, ht, hp, idx);
    k_l0<<<1024, 256, 0, stream>>>(lf, hT, idx, W0b, b0, y0, gpart);
    k_red<<<256, 256, 0, stream>>>(gpart, gstat);
    k_l1<<<1024, 256, 0, stream>>>(y0, g0, be0, W1b, b1, gstat, gpart);
    k_red<<<256, 256, 0, stream>>>(gpart, gstat + 256);
    k_bn1<<<4096, 256, 0, stream>>>(y0, gstat, g1, be1, (float*)d_out);
}